// Round 8
// baseline (485.549 us; speedup 1.0000x reference)
//
#include <hip/hip_runtime.h>
#include <math.h>

#define DIM    1024
#define HEADS  16
#define HD     64
#define SEQ    2048
#define BATCH  2
#define TTOK   4096   // BATCH*SEQ
#define DFF    4096
#define S3     3072   // fused QKV row stride

typedef __attribute__((ext_vector_type(8))) short short8;
typedef __attribute__((ext_vector_type(4))) float f32x4;

__device__ __forceinline__ float bf2f(unsigned short u) {
  union { unsigned int u; float f; } v; v.u = ((unsigned int)u) << 16; return v.f;
}
__device__ __forceinline__ unsigned short f2bf(float f) {
  union { float f; unsigned int u; } v; v.f = f;
  return (unsigned short)((v.u + 0x7FFFu + ((v.u >> 16) & 1u)) >> 16);
}
__device__ __forceinline__ unsigned short f2bf_trunc(float f) {
  union { float f; unsigned int u; } v; v.f = f;
  return (unsigned short)(v.u >> 16);
}

#define AS1(p) ((const __attribute__((address_space(1))) void*)(p))
#define AS3(p) ((__attribute__((address_space(3))) void*)(p))

// ---------------------------------------------------------------------------
// Merged weight conversion: all 7 f32 weights -> contiguous bf16 [0,16M).
// ---------------------------------------------------------------------------
__global__ __launch_bounds__(256) void wconv_k(
    const float* __restrict__ s0, const float* __restrict__ s1,
    const float* __restrict__ s2, const float* __restrict__ s3,
    const float* __restrict__ s4, const float* __restrict__ s5,
    const float* __restrict__ s6, unsigned short* __restrict__ dst)
{
  const int i = blockIdx.x * 256 + threadIdx.x;   // 0..4194303
  const float* s; int base;
  if (i < 1048576) {
    if (i < 524288) { if (i < 262144) { s = s0; base = 0; } else { s = s1; base = 262144; } }
    else            { if (i < 786432) { s = s2; base = 524288; } else { s = s3; base = 786432; } }
  } else if (i < 2097152) { s = s4; base = 1048576; }
  else if (i < 3145728)   { s = s5; base = 2097152; }
  else                    { s = s6; base = 3145728; }
  const float4 f = ((const float4*)s)[i - base];
  unsigned long long o = (unsigned long long)f2bf(f.x)
                       | ((unsigned long long)f2bf(f.y) << 16)
                       | ((unsigned long long)f2bf(f.z) << 32)
                       | ((unsigned long long)f2bf(f.w) << 48);
  ((unsigned long long*)dst)[i] = o;
}

// ---------------------------------------------------------------------------
// GEMM: C[M,N] = A[M,K] bf16 x W[N,K]^T bf16. 128x128 tile, BK=64, 4 waves,
// 16x16x32 MFMA, global_load_lds w=16, XOR-8 swizzle.
// 1-D grid + XCD-aware block swizzle: lid%8 = XCD (round-robin dispatch
// heuristic); each XCD owns ncol/8 contiguous column-groups x 32 row-blocks
// so the concurrent weight footprint per XCD (<=1.5MB) fits its 4MB L2.
// MODE 3: Cf = v + resf (f32 out)
// MODE 5: C = v with RoPE on cols<2048 (fused QKV, N=3072)
// MODE 6: split-K partial (z = lid>>8 selects K-chunk and partial region)
// ---------------------------------------------------------------------------
template<int MODE>
__global__ __launch_bounds__(256) void gemm_bt(
    const unsigned short* __restrict__ A,
    const unsigned short* __restrict__ W,
    unsigned short* __restrict__ C,
    float* __restrict__ Cf,
    const float* __restrict__ resf,
    const float* __restrict__ cosp,
    const float* __restrict__ sinp,
    int M, int N, int K, int ncol)
{
  __shared__ __align__(16) unsigned short As[128 * 64];
  __shared__ __align__(16) unsigned short Bs[128 * 64];

  const int tid  = threadIdx.x;
  const int lane = tid & 63;
  const int wv   = tid >> 6;

  int lid = blockIdx.x;
  int kb = 0, ke = K, zz = 0;
  if (MODE == 6) { zz = lid >> 8; lid &= 255; kb = zz * 1024; ke = kb + 1024; }
  const int xcd  = lid & 7;
  const int slot = lid >> 3;
  const int cpx  = ncol >> 3;
  const int row0 = (slot & 31) * 128;
  const int col0 = (xcd * cpx + (slot >> 5)) * 128;

  const int wm   = (wv >> 1) * 64;
  const int wn   = (wv & 1) * 64;
  const int lr   = lane & 15;
  const int lg   = lane >> 4;

  const int srow = lane >> 3;
  const int skg  = (lane & 7) ^ srow;

  f32x4 acc[4][4];
#pragma unroll
  for (int i = 0; i < 4; i++)
#pragma unroll
    for (int j = 0; j < 4; j++) acc[i][j] = (f32x4){0.f, 0.f, 0.f, 0.f};

  for (int k0 = kb; k0 < ke; k0 += 64) {
#pragma unroll
    for (int i = 0; i < 4; i++) {
      const int c = wv * 4 + i;
      const unsigned short* ga = A + (size_t)(row0 + c * 8 + srow) * K + k0 + skg * 8;
      __builtin_amdgcn_global_load_lds(AS1(ga), AS3(As + c * 512), 16, 0, 0);
      const unsigned short* gb = W + (size_t)(col0 + c * 8 + srow) * K + k0 + skg * 8;
      __builtin_amdgcn_global_load_lds(AS1(gb), AS3(Bs + c * 512), 16, 0, 0);
    }
    __syncthreads();

#pragma unroll
    for (int ks = 0; ks < 2; ks++) {
      short8 af[4], bf[4];
#pragma unroll
      for (int i = 0; i < 4; i++) {
        const int r = wm + i * 16 + lr;
        af[i] = *(const short8*)(As + r * 64 + (((ks * 4 + lg) ^ (lr & 7)) * 8));
      }
#pragma unroll
      for (int j = 0; j < 4; j++) {
        const int r = wn + j * 16 + lr;
        bf[j] = *(const short8*)(Bs + r * 64 + (((ks * 4 + lg) ^ (lr & 7)) * 8));
      }
#pragma unroll
      for (int i = 0; i < 4; i++)
#pragma unroll
        for (int j = 0; j < 4; j++)
          acc[i][j] = __builtin_amdgcn_mfma_f32_16x16x32_bf16(af[i], bf[j], acc[i][j], 0, 0, 0);
    }
    __syncthreads();
  }

  // epilogue: C/D layout col=lane&15, row=(lane>>4)*4+r  [m89/m91]
  if (MODE == 5) {
    const bool do_rope = (col0 < 2048);
#pragma unroll
    for (int i = 0; i < 4; i++) {
#pragma unroll
      for (int r = 0; r < 4; r++) {
        const int row = row0 + wm + i * 16 + lg * 4 + r;
        const int s = row & (SEQ - 1);
        const size_t rb = (size_t)row * N + col0 + wn;
        if (do_rope) {
#pragma unroll
          for (int jp = 0; jp < 2; jp++) {
            const int d = jp * 16 + lr;
            const float c = cosp[s * HD + d];
            const float sn = sinp[s * HD + d];
            const float x1v = acc[i][jp][r];
            const float x2v = acc[i][jp + 2][r];
            C[rb + d]      = f2bf(x1v * c - x2v * sn);
            C[rb + d + 32] = f2bf(x2v * c + x1v * sn);
          }
        } else {
#pragma unroll
          for (int j = 0; j < 4; j++)
            C[rb + j * 16 + lr] = f2bf(acc[i][j][r]);
        }
      }
    }
    return;
  }

  unsigned short* Cz = C;
  if (MODE == 6) {
    const size_t pz[4] = {4u * 1048576u, 8u * 1048576u, 16u * 1048576u, 0u};
    Cz = C + pz[zz];
  }
#pragma unroll
  for (int i = 0; i < 4; i++) {
#pragma unroll
    for (int j = 0; j < 4; j++) {
      const int col = col0 + wn + j * 16 + lr;
#pragma unroll
      for (int r = 0; r < 4; r++) {
        const int row = row0 + wm + i * 16 + lg * 4 + r;
        const float v = acc[i][j][r];
        const size_t idx = (size_t)row * N + col;
        if (MODE == 3) {
          Cf[idx] = v + resf[idx];
        } else if (MODE == 6) {
          Cz[idx] = f2bf(v);
        }
      }
    }
  }
}

// ---------------------------------------------------------------------------
// down-proj split-K combine: out += sigmoid(gate) * (P0+P1+P2+P3 + db)
// ---------------------------------------------------------------------------
__global__ __launch_bounds__(256) void dcomb_k(
    const unsigned short* __restrict__ ws, float* __restrict__ out,
    const float* __restrict__ db, const float* __restrict__ gate)
{
  const int i4 = blockIdx.x * 256 + threadIdx.x;   // 1M threads x 4 elems
  const size_t idx = (size_t)i4 * 4;
  const int col = (int)(idx & 1023);
  const unsigned long long p0 = *(const unsigned long long*)(ws + 4u * 1048576u + idx);
  const unsigned long long p1 = *(const unsigned long long*)(ws + 8u * 1048576u + idx);
  const unsigned long long p2 = *(const unsigned long long*)(ws + 16u * 1048576u + idx);
  const unsigned long long p3 = *(const unsigned long long*)(ws + idx);
  float4 o = *(float4*)(out + idx);
  float* op = (float*)&o;
#pragma unroll
  for (int w = 0; w < 4; w++) {
    const float s = bf2f((unsigned short)(p0 >> (16 * w)))
                  + bf2f((unsigned short)(p1 >> (16 * w)))
                  + bf2f((unsigned short)(p2 >> (16 * w)))
                  + bf2f((unsigned short)(p3 >> (16 * w)))
                  + db[col + w];
    const float sg = 1.0f / (1.0f + __expf(-gate[col + w]));
    op[w] += sg * s;
  }
  *(float4*)(out + idx) = o;
}

// ---------------------------------------------------------------------------
// Fused SwiGLU GEMM: G[M,N] = silu(A Wg^T + gb) * (A Wu^T + ub).
// 1-D grid (1024) with XCD swizzle: each XCD owns 4 contiguous column-groups.
// ---------------------------------------------------------------------------
__global__ __launch_bounds__(256) void gemm_swiglu(
    const unsigned short* __restrict__ A,
    const unsigned short* __restrict__ Wg,
    const unsigned short* __restrict__ Wu,
    unsigned short* __restrict__ G,
    const float* __restrict__ gb,
    const float* __restrict__ ub,
    int M, int N, int K)
{
  __shared__ __align__(16) unsigned short As[128 * 64];
  __shared__ __align__(16) unsigned short Gs[128 * 64];
  __shared__ __align__(16) unsigned short Us[128 * 64];

  const int tid  = threadIdx.x;
  const int lane = tid & 63;
  const int wv   = tid >> 6;

  const int lid  = blockIdx.x;
  const int xcd  = lid & 7;
  const int slot = lid >> 3;                 // 0..127
  const int row0 = (slot & 31) * 128;
  const int col0 = (xcd * 4 + (slot >> 5)) * 128;

  const int wm   = (wv >> 1) * 64;
  const int wn   = (wv & 1) * 64;
  const int lr   = lane & 15;
  const int lg   = lane >> 4;

  const int srow = lane >> 3;
  const int skg  = (lane & 7) ^ srow;

  f32x4 ag[4][4], au[4][4];
#pragma unroll
  for (int i = 0; i < 4; i++)
#pragma unroll
    for (int j = 0; j < 4; j++) {
      ag[i][j] = (f32x4){0.f, 0.f, 0.f, 0.f};
      au[i][j] = (f32x4){0.f, 0.f, 0.f, 0.f};
    }

  for (int k0 = 0; k0 < K; k0 += 64) {
#pragma unroll
    for (int i = 0; i < 4; i++) {
      const int c = wv * 4 + i;
      const unsigned short* ga = A + (size_t)(row0 + c * 8 + srow) * K + k0 + skg * 8;
      __builtin_amdgcn_global_load_lds(AS1(ga), AS3(As + c * 512), 16, 0, 0);
      const unsigned short* gg = Wg + (size_t)(col0 + c * 8 + srow) * K + k0 + skg * 8;
      __builtin_amdgcn_global_load_lds(AS1(gg), AS3(Gs + c * 512), 16, 0, 0);
      const unsigned short* gu = Wu + (size_t)(col0 + c * 8 + srow) * K + k0 + skg * 8;
      __builtin_amdgcn_global_load_lds(AS1(gu), AS3(Us + c * 512), 16, 0, 0);
    }
    __syncthreads();

#pragma unroll
    for (int ks = 0; ks < 2; ks++) {
      short8 af[4], bg[4], bu[4];
#pragma unroll
      for (int i = 0; i < 4; i++) {
        const int r = wm + i * 16 + lr;
        af[i] = *(const short8*)(As + r * 64 + (((ks * 4 + lg) ^ (lr & 7)) * 8));
      }
#pragma unroll
      for (int j = 0; j < 4; j++) {
        const int r = wn + j * 16 + lr;
        const int off = (((ks * 4 + lg) ^ (lr & 7)) * 8);
        bg[j] = *(const short8*)(Gs + r * 64 + off);
        bu[j] = *(const short8*)(Us + r * 64 + off);
      }
#pragma unroll
      for (int i = 0; i < 4; i++)
#pragma unroll
        for (int j = 0; j < 4; j++) {
          ag[i][j] = __builtin_amdgcn_mfma_f32_16x16x32_bf16(af[i], bg[j], ag[i][j], 0, 0, 0);
          au[i][j] = __builtin_amdgcn_mfma_f32_16x16x32_bf16(af[i], bu[j], au[i][j], 0, 0, 0);
        }
    }
    __syncthreads();
  }

#pragma unroll
  for (int i = 0; i < 4; i++) {
#pragma unroll
    for (int j = 0; j < 4; j++) {
      const int col = col0 + wn + j * 16 + lr;
#pragma unroll
      for (int r = 0; r < 4; r++) {
        const int row = row0 + wm + i * 16 + lg * 4 + r;
        float g = ag[i][j][r] + gb[col];
        g = g / (1.0f + __expf(-g));
        const float u = au[i][j][r] + ub[col];
        G[(size_t)row * N + col] = f2bf(g * u);
      }
    }
  }
}

// ---------------------------------------------------------------------------
template<int XF32>
__global__ __launch_bounds__(256) void rmsnorm_k(
    const void* __restrict__ Xv,
    const float* __restrict__ W,
    unsigned short* __restrict__ Y)
{
  const int t  = blockIdx.x;
  const int i0 = threadIdx.x * 4;

  float v[4];
  if (XF32) {
    const float4 f = *(const float4*)((const float*)Xv + (size_t)t * DIM + i0);
    v[0] = f.x; v[1] = f.y; v[2] = f.z; v[3] = f.w;
  } else {
    unsigned long long raw = *(const unsigned long long*)((const unsigned short*)Xv + (size_t)t * DIM + i0);
#pragma unroll
    for (int k = 0; k < 4; k++) v[k] = bf2f((unsigned short)(raw >> (16 * k)));
  }

  float ss = v[0] * v[0] + v[1] * v[1] + v[2] * v[2] + v[3] * v[3];
#pragma unroll
  for (int off = 32; off > 0; off >>= 1) ss += __shfl_xor(ss, off);

  __shared__ float red[4];
  if ((threadIdx.x & 63) == 0) red[threadIdx.x >> 6] = ss;
  __syncthreads();
  const float tot = red[0] + red[1] + red[2] + red[3];
  const float r = rsqrtf(tot * (1.0f / DIM) + 1e-5f);

  const float4 wf = *(const float4*)(W + i0);
  const float wv4[4] = {wf.x, wf.y, wf.z, wf.w};
  unsigned long long o = 0;
#pragma unroll
  for (int k = 0; k < 4; k++)
    o |= ((unsigned long long)f2bf(v[k] * r * wv4[k])) << (16 * k);
  *(unsigned long long*)(Y + (size_t)t * DIM + i0) = o;
}

// ---------------------------------------------------------------------------
// Split-K MFMA flash attention, fixed-max softmax, balanced static schedule.
// (unchanged from round 7 — see comments there)
// ---------------------------------------------------------------------------
__device__ const unsigned char cqt[32] = {10,10,15,15,9,9,13,14,14,14,15,4,8,8,12,12,13,13,7,7,11,11,11,12,3,6,6,5,5,2,1,0};
__device__ const unsigned char ctb[32] = {0,11,0,11,0,10,0,0,10,20,22,0,0,9,0,9,10,19,0,8,0,8,16,18,0,0,7,0,6,0,0,0};
__device__ const unsigned char ccnt[32] = {11,11,11,11,10,10,10,10,10,10,10,10,9,9,9,9,9,9,8,8,8,8,8,8,8,7,7,6,6,6,4,2};
__device__ const unsigned char cchv[32] = {0,1,0,1,0,1,0,0,1,2,2,0,0,1,0,1,1,2,0,1,0,1,2,2,0,0,1,0,1,0,0,0};
__device__ const unsigned char cpsv[32] = {255,5,255,14,255,4,255,255,12,13,15,255,255,3,255,8,10,11,255,2,255,6,7,9,255,255,1,255,0,255,255,255};

__global__ __launch_bounds__(256) void fattn_k(
    const unsigned short* __restrict__ QKV,   // [TTOK][3072]
    unsigned short* __restrict__ O,           // [TTOK][1024]
    unsigned short* __restrict__ Pbuf,        // 32bh x 16 slots x 128x64
    float* __restrict__ Lbuf)                 // 32bh x 11qt x 3ch x 128
{
  __shared__ __align__(16) unsigned short Ks[2][64 * 64];   // 16 KB
  __shared__ __align__(16) unsigned short Vt[2][64 * 72];   // 18 KB
  __shared__ __align__(16) unsigned short Ps[4 * 32 * 72];  // 18 KB

  const int tid  = threadIdx.x;
  const int lane = tid & 63;
  const int wv   = tid >> 6;
  const int lr   = lane & 15;
  const int lg   = lane >> 4;

  const int j  = blockIdx.x;
  const int bh = blockIdx.y;
  const int qt = cqt[j];
  const int tb = ctb[j];
  const int nt = ccnt[j];
  const int ch = cchv[j];
  const int ps = cpsv[j];
  const int b  = bh >> 4, h = bh & 15;
  const int q0 = qt * 128;
  const size_t rowb = (size_t)b * SEQ;
  const int qoff = h * HD;
  const int koff = 1024 + qoff;
  const int voff = 2048 + qoff;

  short8 aq[2][2];
#pragma unroll
  for (int rf = 0; rf < 2; rf++) {
    const size_t tok = rowb + q0 + wv * 32 + rf * 16 + lr;
    aq[rf][0] = *(const short8*)(QKV + tok * S3 + qoff + lg * 8);
    aq[rf][1] = *(const short8*)(QKV + tok * S3 + qoff + 32 + lg * 8);
  }

  f32x4 o[2][4];
  f32x4 lacc[2];
#pragma unroll
  for (int rf = 0; rf < 2; rf++) {
    lacc[rf] = (f32x4){0.f, 0.f, 0.f, 0.f};
#pragma unroll
    for (int d = 0; d < 4; d++) o[rf][d] = (f32x4){0.f, 0.f, 0.f, 0.f};
  }
  short8 onesb;
#pragma unroll
  for (int jj = 0; jj < 8; jj++) onesb[jj] = (short)0x3F80;   // bf16 1.0

  const int srow = lane >> 3;
  const int skg  = (lane & 7) ^ srow;
  const int kv   = tid >> 2;
  const int d0   = (tid & 3) * 16;

  const float C1 = 0.125f * 1.44269504f;   // scale * log2e
  const float C2 = 11.5415603f;            // 8 * log2e

  auto stage = [&](int buf, int ti) {
    const int t0 = (tb + ti) * 64;
    unsigned short* ksb = &Ks[buf][0];
#pragma unroll
    for (int i = 0; i < 2; i++) {
      const int c = wv * 2 + i;
      const unsigned short* gk = QKV + (rowb + t0 + c * 8 + srow) * S3 + koff + skg * 8;
      __builtin_amdgcn_global_load_lds(AS1(gk), AS3(ksb + c * 512), 16, 0, 0);
    }
    unsigned short* vtb = &Vt[buf][0];
    const unsigned short* gv = QKV + (rowb + t0 + kv) * S3 + voff + d0;
    const short8 v0 = *(const short8*)gv;
    const short8 v1 = *(const short8*)(gv + 8);
    const int klo = kv & 7, khi = kv >> 3;
#pragma unroll
    for (int w = 0; w < 8; w++) {
      const int da = d0 + w, db2 = d0 + 8 + w;
      vtb[da  * 72 + ((khi ^ ((da  >> 3) & 7)) * 8) + klo] = (unsigned short)v0[w];
      vtb[db2 * 72 + ((khi ^ ((db2 >> 3) & 7)) * 8) + klo] = (unsigned short)v1[w];
    }
  };

  stage(0, 0);

  for (int ti = 0; ti < nt; ti++) {
    __syncthreads();
    if (ti + 1 < nt) stage((ti + 1) & 1, ti + 1);

    const int t0 = (tb + ti) * 64;
    const unsigned short* ksb = &Ks[ti & 1][0];
    const unsigned short* vtb = &Vt[ti & 1][0];

    f32x4 S[2][4];
#pragma unroll
    for (int sub = 0; sub < 4; sub++) {
      const int kr = sub * 16 + lr;
      const short8 bk0 = *(const short8*)(ksb + kr * 64 + ((lg       ^ (kr & 7)) * 8));
      const short8 bk1 = *(const short8*)(ksb + kr * 64 + (((4 + lg) ^ (kr & 7)) * 8));
#pragma unroll
      for (int rf = 0; rf < 2; rf++) {
        f32x4 s = (f32x4){0.f, 0.f, 0.f, 0.f};
        s = __builtin_amdgcn_mfma_f32_16x16x32_bf16(aq[rf][0], bk0, s, 0, 0, 0);
        s = __builtin_amdgcn_mfma_f32_16x16x32_bf16(aq[rf][1], bk1, s, 0, 0, 0);
        S[rf][sub] = s;
      }
    }

    unsigned short* pw = Ps + wv * (32 * 72);
#pragma unroll
    for (int rf = 0; rf < 2; rf++) {
      const int qmin = q0 + wv * 32 + rf * 16;
      const bool diag = (t0 + 63 > qmin);
#pragma unroll
      for (int sub = 0; sub < 4; sub++) {
#pragma unroll
        for (int r = 0; r < 4; r++) {
          float t = fmaf(S[rf][sub][r], C1, -C2);
          if (diag && (t0 + sub * 16 + lr > qmin + lg * 4 + r)) t = -INFINITY;
          const float p = exp2f(t);
          pw[(rf * 16 + lg * 4 + r) * 72 + sub * 16 + lr] = f2bf_trunc(p);
        }
      }
    }

#pragma unroll
    for (int kf = 0; kf < 2; kf++) {
      const short8 pa0 = *(const short8*)(pw + lr * 72 + kf * 32 + lg * 8);
      const short8 pa1 = *(const short8*)(pw + (16 + lr) * 72 + kf * 32 + lg * 8);
      lacc[0] = __builtin_amdgcn_mfma_f32_16x16x32_bf16(pa0, onesb, lacc[0], 0, 0, 0);
      lacc[1] = __builtin_amdgcn_mfma_f32_16x16x32_bf16(pa1, onesb, lacc[1], 0, 0, 0);
#pragma unroll
      for (int dsub = 0; dsub < 4; dsub++) {
        const int d = dsub * 16 + lr;
        const short8 bvf = *(const short8*)(vtb + d * 72 +
                             (((kf * 4 + lg) ^ ((d >> 3) & 7)) * 8));
        o[0][dsub] = __builtin_amdgcn_mfma_f32_16x16x32_bf16(pa0, bvf, o[0][dsub], 0, 0, 0);
        o[1][dsub] = __builtin_amdgcn_mfma_f32_16x16x32_bf16(pa1, bvf, o[1][dsub], 0, 0, 0);
      }
    }
  }

  if (ps == 255 && qt < 5) {
#pragma unroll
    for (int rf = 0; rf < 2; rf++) {
      float inv[4];
#pragma unroll
      for (int r = 0; r < 4; r++) inv[r] = 1.0f / lacc[rf][r];
#pragma unroll
      for (int dsub = 0; dsub < 4; dsub++)
#pragma unroll
        for (int r = 0; r < 4; r++)
          O[(rowb + q0 + wv * 32 + rf * 16 + lg * 4 + r) * DIM + h * HD + dsub * 16 + lr] =
              f2bf(o[rf][dsub][r] * inv[r]);
    }
  } else {
    const int lbase = ((bh * 11 + (qt - 5)) * 3 + ch) * 128;
#pragma unroll
    for (int rf = 0; rf < 2; rf++) {
      const int rbase = wv * 32 + rf * 16 + lg * 4;
      if (lr == 0) {
#pragma unroll
        for (int r = 0; r < 4; r++) Lbuf[lbase + rbase + r] = lacc[rf][r];
      }
    }
    if (ps == 255) {
#pragma unroll
      for (int rf = 0; rf < 2; rf++)
#pragma unroll
        for (int dsub = 0; dsub < 4; dsub++)
#pragma unroll
          for (int r = 0; r < 4; r++)
            O[(rowb + q0 + wv * 32 + rf * 16 + lg * 4 + r) * DIM + h * HD + dsub * 16 + lr] =
                f2bf(o[rf][dsub][r]);
    } else {
      unsigned short* pb = Pbuf + ((size_t)bh * 16 + ps) * 8192;
#pragma unroll
      for (int rf = 0; rf < 2; rf++) {
        const int rbase = wv * 32 + rf * 16 + lg * 4;
#pragma unroll
        for (int dsub = 0; dsub < 4; dsub++)
#pragma unroll
          for (int r = 0; r < 4; r++)
            pb[(rbase + r) * 64 + dsub * 16 + lr] = f2bf(o[rf][dsub][r]);
      }
    }
  }
}

// ---------------------------------------------------------------------------
__global__ __launch_bounds__(256) void fattn_combine_k(
    const unsigned short* __restrict__ Pbuf,
    const float* __restrict__ Lbuf,
    unsigned short* __restrict__ O)
{
  const int qt = 5 + blockIdx.x;
  const int bh = blockIdx.y;
  const int b  = bh >> 4, h = bh & 15;
  const int q0 = qt * 128;
  const size_t rowb = (size_t)b * SEQ;
  const int pbase_t[11] = {0, 1, 2, 3, 4, 5, 6, 8, 10, 12, 14};
  const int pb0 = pbase_t[qt - 5];
  const int np  = (qt < 11) ? 1 : 2;
  const int lbase = (bh * 11 + (qt - 5)) * 3 * 128;

  const unsigned short* p0 = Pbuf + ((size_t)bh * 16 + pb0) * 8192;
  const unsigned short* p1 = Pbuf + ((size_t)bh * 16 + pb0 + 1) * 8192;

#pragma unroll
  for (int it = 0; it < 4; it++) {
    const int idx = it * 2048 + threadIdx.x * 8;
    const int row = idx >> 6;
    const int col = idx & 63;
    float ls = Lbuf[lbase + row] + Lbuf[lbase + 128 + row];
    if (np == 2) ls += Lbuf[lbase + 256 + row];
    const float inv = 1.0f / ls;

    unsigned short* op = O + (rowb + q0 + row) * DIM + h * HD + col;
    const short8 vb = *(const short8*)op;
    const short8 e0 = *(const short8*)(p0 + idx);
    short8 e1;
    if (np == 2) e1 = *(const short8*)(p1 + idx);
    short8 r;
#pragma unroll
    for (int w = 0; w < 8; w++) {
      float s = bf2f((unsigned short)vb[w]) + bf2f((unsigned short)e0[w]);
      if (np == 2) s += bf2f((unsigned short)e1[w]);
      r[w] = (short)f2bf(s * inv);
    }
    *(short8*)op = r;
  }
}

// ---------------------------------------------------------------------------
// Workspace (bf16 elems, 1M = 1<<20), high-water 36M = 72 MB (same as r7).
// ---------------------------------------------------------------------------
extern "C" void kernel_launch(void* const* d_in, const int* in_sizes, int n_in,
                              void* d_out, int out_size, void* d_ws, size_t ws_size,
                              hipStream_t stream)
{
  const float* h    = (const float*)d_in[0];
  const float* cosb = (const float*)d_in[1];
  const float* sinb = (const float*)d_in[2];
  const float* n1w  = (const float*)d_in[3];
  const float* n2w  = (const float*)d_in[8];
  const float* gb   = (const float*)d_in[10];
  const float* ub   = (const float*)d_in[12];
  const float* db   = (const float*)d_in[14];
  const float* gatep= (const float*)d_in[15];
  float* out = (float*)d_out;

  unsigned short* ws = (unsigned short*)d_ws;
  const size_t M1 = 1u << 20;

  unsigned short* wqkv = ws;                  // wq@0, wk@1M, wv@2M
  unsigned short* wo_c = ws + 3 * M1;
  unsigned short* gw_c = ws + 4 * M1;
  unsigned short* uw_c = ws + 8 * M1;
  unsigned short* dw_c = ws + 12 * M1;
  unsigned short* x1   = ws + 16 * M1;
  unsigned short* Pbuf = ws + 16 * M1;        // overlay (x1 dead during fattn)
  unsigned short* x2   = ws + 16 * M1;        // overlay (Pbuf dead after combine)
  float*          Lbuf = (float*)ws;          // overlay on dead wqkv
  unsigned short* qkv  = ws + 20 * M1;        // 12M
  unsigned short* attn = ws + 32 * M1;        // 4M
  unsigned short* g    = qkv;                 // 16M over qkv+attn (both dead)

  const dim3 blk(256);

  wconv_k<<<16384, blk, 0, stream>>>(
      (const float*)d_in[4], (const float*)d_in[5], (const float*)d_in[6],
      (const float*)d_in[7], (const float*)d_in[9], (const float*)d_in[11],
      (const float*)d_in[13], ws);

  rmsnorm_k<1><<<TTOK, blk, 0, stream>>>(h, n1w, x1);

  // qkv = x1 @ [wq;wk;wv]^T with RoPE fused (768 blocks, 24 col-groups)
  gemm_bt<5><<<768, blk, 0, stream>>>(x1, wqkv, qkv, nullptr, nullptr,
                                      cosb, sinb, TTOK, S3, DIM, 24);

  fattn_k<<<dim3(32, BATCH * HEADS), blk, 0, stream>>>(qkv, attn, Pbuf, Lbuf);
  fattn_combine_k<<<dim3(11, BATCH * HEADS), blk, 0, stream>>>(Pbuf, Lbuf, attn);

  // h2(f32, in d_out) = attn @ wo^T + h   (256 blocks, 8 col-groups)
  gemm_bt<3><<<256, blk, 0, stream>>>(attn, wo_c, nullptr, out, h,
                                      nullptr, nullptr, TTOK, DIM, DIM, 8);

  rmsnorm_k<1><<<TTOK, blk, 0, stream>>>(out, n2w, x2);

  // g = silu(x2 gw^T + gb) * (x2 uw^T + ub)   (1024 blocks, XCD swizzle)
  gemm_swiglu<<<1024, blk, 0, stream>>>(x2, gw_c, uw_c, g, gb, ub, TTOK, DFF, DIM);

  // down-proj split-K x4 (1024 blocks: z = lid>>8, 8 col-groups per slice)
  gemm_bt<6><<<1024, blk, 0, stream>>>(g, dw_c, ws, nullptr, nullptr,
                                       nullptr, nullptr, TTOK, DIM, DFF, 8);

  // out += sigmoid(gate) * (P0+P1+P2+P3 + db)
  dcomb_k<<<4096, blk, 0, stream>>>(ws, out, db, gatep);
}